// Round 1
// baseline (1603.409 us; speedup 1.0000x reference)
//
#include <hip/hip_runtime.h>

// GCN: out = GCNConv2( relu( GCNConv1(x) ) )
// GCNConv(x,W,b): h = x@W; deg = indeg(dst incl self); dinv = rsqrt(deg);
//                 out[i] = sum_{e: dst=i} dinv[src]*dinv[dst]*h[src] + b
// (src/dst include self-loops: src=dst=i for every node)

constexpr int NN = 50000;
constexpr int NE = 800000;
constexpr int DI = 96;
constexpr int DH = 96;
constexpr int DO = 48;

// ---------------- degree / norm ----------------

__global__ void k_fill1(float* __restrict__ deg, int n) {
    int i = blockIdx.x * blockDim.x + threadIdx.x;
    if (i < n) deg[i] = 1.0f;  // self-loop contributes 1
}

__global__ void k_deg(const int* __restrict__ dst, float* __restrict__ deg, int e) {
    int i = blockIdx.x * blockDim.x + threadIdx.x;
    if (i < e) atomicAdd(&deg[dst[i]], 1.0f);
}

__global__ void k_rsqrt(float* __restrict__ deg, int n) {
    int i = blockIdx.x * blockDim.x + threadIdx.x;
    if (i < n) deg[i] = rsqrtf(deg[i]);
}

// ---------------- dense GEMM: H[n][DOUT] = X[n][DI] @ W[DI][DOUT] ----------------
// block = 256 threads, 32 rows/block. thread tile = 2 rows x (DOUT/16) cols.

template<int DOUT>
__global__ __launch_bounds__(256) void k_gemm(const float* __restrict__ X,
                                              const float* __restrict__ W,
                                              float* __restrict__ H, int n) {
    constexpr int ROWS = 32;
    constexpr int CPT  = DOUT / 16;  // cols per thread (6 or 3)
    constexpr int RPT  = 2;          // rows per thread

    __shared__ float ws[DI * DOUT];
    __shared__ float xs[ROWS][DI];

    const int tid  = threadIdx.x;
    const int row0 = blockIdx.x * ROWS;

    for (int i = tid; i < DI * DOUT; i += 256) ws[i] = W[i];

    {
        const float4* Xv  = reinterpret_cast<const float4*>(X + (size_t)row0 * DI);
        float4*       xsv = reinterpret_cast<float4*>(&xs[0][0]);
        const int nv   = ROWS * DI / 4;                  // 768
        const int maxv = ((n - row0) * DI) / 4;          // valid float4s for tail block
        for (int i = tid; i < nv; i += 256) {
            float4 v = (i < maxv) ? Xv[i] : float4{0.f, 0.f, 0.f, 0.f};
            xsv[i] = v;
        }
    }
    __syncthreads();

    const int cg = tid & 15;   // col group 0..15 (contiguous lanes -> contiguous cols)
    const int rg = tid >> 4;   // row group 0..15

    float acc[RPT][CPT];
#pragma unroll
    for (int i = 0; i < RPT; ++i)
#pragma unroll
        for (int j = 0; j < CPT; ++j) acc[i][j] = 0.f;

    for (int k = 0; k < DI; ++k) {
        float xv[RPT];
#pragma unroll
        for (int i = 0; i < RPT; ++i) xv[i] = xs[rg * RPT + i][k];
#pragma unroll
        for (int j = 0; j < CPT; ++j) {
            float wv = ws[k * DOUT + cg * CPT + j];
#pragma unroll
            for (int i = 0; i < RPT; ++i) acc[i][j] += xv[i] * wv;
        }
    }

#pragma unroll
    for (int i = 0; i < RPT; ++i) {
        int row = row0 + rg * RPT + i;
        if (row < n) {
#pragma unroll
            for (int j = 0; j < CPT; ++j)
                H[(size_t)row * DOUT + cg * CPT + j] = acc[i][j];
        }
    }
}

// ---------------- self-loop init: out[i] = dinv[i]^2 * h[i] (+ bias) ----------------

template<int D>
__global__ void k_self_init(const float* __restrict__ h, const float* __restrict__ dinv,
                            const float* __restrict__ bias, float* __restrict__ out, int n) {
    constexpr int G = D / 4;
    int t = blockIdx.x * blockDim.x + threadIdx.x;
    int total = n * G;
    if (t >= total) return;
    int node = t / G;
    int g    = t % G;
    float di = dinv[node];
    float s  = di * di;
    float4 hv = reinterpret_cast<const float4*>(h)[t];
    float4 o;
    o.x = s * hv.x; o.y = s * hv.y; o.z = s * hv.z; o.w = s * hv.w;
    if (bias != nullptr) {
        float4 bv = reinterpret_cast<const float4*>(bias)[g];
        o.x += bv.x; o.y += bv.y; o.z += bv.z; o.w += bv.w;
    }
    reinterpret_cast<float4*>(out)[t] = o;
}

// ---------------- edge scatter: out[dst] += dinv[src]*dinv[dst] * h[src] ----------------

template<int D>
__global__ void k_agg(const int* __restrict__ src, const int* __restrict__ dst,
                      const float* __restrict__ dinv, const float* __restrict__ h,
                      float* __restrict__ out, int e) {
    constexpr int G = D / 4;
    long long t = (long long)blockIdx.x * blockDim.x + threadIdx.x;
    long long total = (long long)e * G;
    if (t >= total) return;
    int eid = (int)(t / G);
    int g   = (int)(t % G);
    int s = src[eid];
    int d = dst[eid];
    float nrm = dinv[s] * dinv[d];
    float4 hv = reinterpret_cast<const float4*>(h)[(size_t)s * G + g];
    float* o = out + (size_t)d * D + g * 4;
    atomicAdd(o + 0, nrm * hv.x);
    atomicAdd(o + 1, nrm * hv.y);
    atomicAdd(o + 2, nrm * hv.z);
    atomicAdd(o + 3, nrm * hv.w);
}

// ---------------- relu + bias (in place) ----------------

__global__ void k_relu_bias(float* __restrict__ a, const float* __restrict__ b, int n) {
    constexpr int G = DH / 4;  // 24
    int t = blockIdx.x * blockDim.x + threadIdx.x;
    int total = n * G;
    if (t >= total) return;
    int g = t % G;
    float4 v  = reinterpret_cast<float4*>(a)[t];
    float4 bv = reinterpret_cast<const float4*>(b)[g];
    v.x = fmaxf(v.x + bv.x, 0.f);
    v.y = fmaxf(v.y + bv.y, 0.f);
    v.z = fmaxf(v.z + bv.z, 0.f);
    v.w = fmaxf(v.w + bv.w, 0.f);
    reinterpret_cast<float4*>(a)[t] = v;
}

// ---------------- launch ----------------

extern "C" void kernel_launch(void* const* d_in, const int* in_sizes, int n_in,
                              void* d_out, int out_size, void* d_ws, size_t ws_size,
                              hipStream_t stream) {
    const float* x   = (const float*)d_in[0];
    const int*   ei  = (const int*)d_in[1];   // [2][NE] (int32 per harness convention)
    const float* W1  = (const float*)d_in[2];
    const float* b1  = (const float*)d_in[3];
    const float* W2  = (const float*)d_in[4];
    const float* b2  = (const float*)d_in[5];
    float*       out = (float*)d_out;

    const int* srcv = ei;
    const int* dstv = ei + NE;

    float* wsf  = (float*)d_ws;
    float* dinv = wsf;                       // NN floats
    float* h1   = dinv + NN;                 // NN*DH floats (reused for h2: NN*DO)
    float* a1   = h1 + (size_t)NN * DH;      // NN*DH floats

    const int B = 256;

    // degrees -> dinv
    k_fill1<<<(NN + B - 1) / B, B, 0, stream>>>(dinv, NN);
    k_deg<<<(NE + B - 1) / B, B, 0, stream>>>(dstv, dinv, NE);
    k_rsqrt<<<(NN + B - 1) / B, B, 0, stream>>>(dinv, NN);

    // layer 1
    k_gemm<DH><<<(NN + 31) / 32, B, 0, stream>>>(x, W1, h1, NN);
    k_self_init<DH><<<(NN * (DH / 4) + B - 1) / B, B, 0, stream>>>(h1, dinv, nullptr, a1, NN);
    {
        long long total = (long long)NE * (DH / 4);
        k_agg<DH><<<(int)((total + B - 1) / B), B, 0, stream>>>(srcv, dstv, dinv, h1, a1, NE);
    }
    k_relu_bias<<<(NN * (DH / 4) + B - 1) / B, B, 0, stream>>>(a1, b1, NN);

    // layer 2 (h2 reuses h1's buffer)
    float* h2 = h1;
    k_gemm<DO><<<(NN + 31) / 32, B, 0, stream>>>(a1, W2, h2, NN);
    k_self_init<DO><<<(NN * (DO / 4) + B - 1) / B, B, 0, stream>>>(h2, dinv, b2, out, NN);
    {
        long long total = (long long)NE * (DO / 4);
        k_agg<DO><<<(int)((total + B - 1) / B), B, 0, stream>>>(srcv, dstv, dinv, h2, out, NE);
    }
}

// Round 2
// 367.089 us; speedup vs baseline: 4.3679x; 4.3679x over previous
//
#include <hip/hip_runtime.h>

// GCN: out = GCNConv2( relu( GCNConv1(x) ) )
// CSR-based aggregation: no float atomics (previous version: every 4B atomicAdd
// wrote ~16B through to HBM -> 1.2GB writes, 993us).

constexpr int NN = 50000;
constexpr int NE = 800000;
constexpr int DI = 96;
constexpr int DH = 96;
constexpr int DO = 48;

// ---------------- CSR build ----------------

__global__ void k_zero_int(int* __restrict__ p, int n) {
    int i = blockIdx.x * blockDim.x + threadIdx.x;
    if (i < n) p[i] = 0;
}

__global__ void k_count(const int* __restrict__ dst, int* __restrict__ cnt, int e) {
    int i = blockIdx.x * blockDim.x + threadIdx.x;
    if (i < e) atomicAdd(&cnt[dst[i]], 1);
}

// single block: exclusive scan of cnt -> row_ptr (+ cursor copy), dinv = rsqrt(cnt+1)
__global__ __launch_bounds__(1024) void k_scan(const int* __restrict__ cnt,
                                               int* __restrict__ row_ptr,
                                               int* __restrict__ cursor,
                                               float* __restrict__ dinv, int n) {
    __shared__ int part[1024];
    const int t = threadIdx.x;
    const int chunk = (n + 1023) / 1024;
    const int lo = t * chunk;
    const int hi = min(lo + chunk, n);
    int s = 0;
    for (int i = lo; i < hi; ++i) s += cnt[i];
    part[t] = s;
    __syncthreads();
    for (int off = 1; off < 1024; off <<= 1) {
        int v = part[t];
        int add = (t >= off) ? part[t - off] : 0;
        __syncthreads();
        part[t] = v + add;
        __syncthreads();
    }
    int run = (t > 0) ? part[t - 1] : 0;  // exclusive prefix of this chunk
    for (int i = lo; i < hi; ++i) {
        row_ptr[i] = run;
        cursor[i]  = run;
        run += cnt[i];
        dinv[i] = rsqrtf((float)(cnt[i] + 1));  // +1 self-loop
    }
}

__global__ void k_fill(const int* __restrict__ src, const int* __restrict__ dst,
                       int* __restrict__ cursor, int* __restrict__ src_sorted, int e) {
    int i = blockIdx.x * blockDim.x + threadIdx.x;
    if (i < e) {
        int pos = atomicAdd(&cursor[dst[i]], 1);
        src_sorted[pos] = src[i];
    }
}

// ---------------- dense GEMM: H[n][DOUT] = X[n][DI] @ W[DI][DOUT] ----------------

template<int DOUT>
__global__ __launch_bounds__(256) void k_gemm(const float* __restrict__ X,
                                              const float* __restrict__ W,
                                              float* __restrict__ H, int n) {
    constexpr int ROWS = 32;
    constexpr int CPT  = DOUT / 16;
    constexpr int RPT  = 2;

    __shared__ float ws[DI * DOUT];
    __shared__ float xs[ROWS][DI];

    const int tid  = threadIdx.x;
    const int row0 = blockIdx.x * ROWS;

    for (int i = tid; i < DI * DOUT; i += 256) ws[i] = W[i];

    {
        const float4* Xv  = reinterpret_cast<const float4*>(X + (size_t)row0 * DI);
        float4*       xsv = reinterpret_cast<float4*>(&xs[0][0]);
        const int nv   = ROWS * DI / 4;
        const int maxv = ((n - row0) * DI) / 4;
        for (int i = tid; i < nv; i += 256) {
            float4 v = (i < maxv) ? Xv[i] : float4{0.f, 0.f, 0.f, 0.f};
            xsv[i] = v;
        }
    }
    __syncthreads();

    const int cg = tid & 15;
    const int rg = tid >> 4;

    float acc[RPT][CPT];
#pragma unroll
    for (int i = 0; i < RPT; ++i)
#pragma unroll
        for (int j = 0; j < CPT; ++j) acc[i][j] = 0.f;

    for (int k = 0; k < DI; ++k) {
        float xv[RPT];
#pragma unroll
        for (int i = 0; i < RPT; ++i) xv[i] = xs[rg * RPT + i][k];
#pragma unroll
        for (int j = 0; j < CPT; ++j) {
            float wv = ws[k * DOUT + cg * CPT + j];
#pragma unroll
            for (int i = 0; i < RPT; ++i) acc[i][j] += xv[i] * wv;
        }
    }

#pragma unroll
    for (int i = 0; i < RPT; ++i) {
        int row = row0 + rg * RPT + i;
        if (row < n) {
#pragma unroll
            for (int j = 0; j < CPT; ++j)
                H[(size_t)row * DOUT + cg * CPT + j] = acc[i][j];
        }
    }
}

// ---------------- CSR aggregation (fused self-loop + bias [+ relu]) ----------------
// thread = (node, 4-dim group); register accumulate, single write.

template<int D, bool RELU>
__global__ __launch_bounds__(256) void k_agg_csr(const float* __restrict__ h,
                                                 const float* __restrict__ dinv,
                                                 const int* __restrict__ row_ptr,
                                                 const int* __restrict__ cnt,
                                                 const int* __restrict__ src_sorted,
                                                 const float* __restrict__ bias,
                                                 float* __restrict__ out, int n) {
    constexpr int G = D / 4;
    int t = blockIdx.x * blockDim.x + threadIdx.x;
    if (t >= n * G) return;
    const int node = t / G;
    const int g    = t % G;

    const float4* h4 = reinterpret_cast<const float4*>(h);
    const float di = dinv[node];
    const float s0 = di * di;

    float4 hv = h4[(size_t)node * G + g];
    float ax = s0 * hv.x, ay = s0 * hv.y, az = s0 * hv.z, aw = s0 * hv.w;

    const int beg = row_ptr[node];
    const int end = beg + cnt[node];
    for (int k = beg; k < end; ++k) {
        int s = src_sorted[k];             // broadcast across the node's G threads
        float nrm = di * dinv[s];
        float4 v = h4[(size_t)s * G + g];  // coalesced 384B/192B row gather
        ax += nrm * v.x;
        ay += nrm * v.y;
        az += nrm * v.z;
        aw += nrm * v.w;
    }

    float4 bv = reinterpret_cast<const float4*>(bias)[g];
    ax += bv.x; ay += bv.y; az += bv.z; aw += bv.w;
    if (RELU) {
        ax = fmaxf(ax, 0.f); ay = fmaxf(ay, 0.f);
        az = fmaxf(az, 0.f); aw = fmaxf(aw, 0.f);
    }
    reinterpret_cast<float4*>(out)[t] = float4{ax, ay, az, aw};
}

// ---------------- launch ----------------

extern "C" void kernel_launch(void* const* d_in, const int* in_sizes, int n_in,
                              void* d_out, int out_size, void* d_ws, size_t ws_size,
                              hipStream_t stream) {
    const float* x   = (const float*)d_in[0];
    const int*   ei  = (const int*)d_in[1];   // [2][NE] int32
    const float* W1  = (const float*)d_in[2];
    const float* b1  = (const float*)d_in[3];
    const float* W2  = (const float*)d_in[4];
    const float* b2  = (const float*)d_in[5];
    float*       out = (float*)d_out;

    const int* srcv = ei;
    const int* dstv = ei + NE;

    // workspace layout
    char* p = (char*)d_ws;
    float* dinv       = (float*)p;            p += (size_t)NN * 4;
    float* h1         = (float*)p;            p += (size_t)NN * DH * 4;   // reused as h2
    float* a1         = (float*)p;            p += (size_t)NN * DH * 4;
    int*   cnt        = (int*)p;              p += (size_t)NN * 4;
    int*   row_ptr    = (int*)p;              p += (size_t)NN * 4;
    int*   cursor     = (int*)p;              p += (size_t)NN * 4;
    int*   src_sorted = (int*)p;              p += (size_t)NE * 4;

    const int B = 256;

    // CSR build + dinv
    k_zero_int<<<(NN + B - 1) / B, B, 0, stream>>>(cnt, NN);
    k_count<<<(NE + B - 1) / B, B, 0, stream>>>(dstv, cnt, NE);
    k_scan<<<1, 1024, 0, stream>>>(cnt, row_ptr, cursor, dinv, NN);
    k_fill<<<(NE + B - 1) / B, B, 0, stream>>>(srcv, dstv, cursor, src_sorted, NE);

    // layer 1: h1 = x@W1 ; a1 = relu(agg(h1) + b1)
    k_gemm<DH><<<(NN + 31) / 32, B, 0, stream>>>(x, W1, h1, NN);
    {
        int total = NN * (DH / 4);
        k_agg_csr<DH, true><<<(total + B - 1) / B, B, 0, stream>>>(
            h1, dinv, row_ptr, cnt, src_sorted, b1, a1, NN);
    }

    // layer 2: h2 = a1@W2 ; out = agg(h2) + b2
    float* h2 = h1;
    k_gemm<DO><<<(NN + 31) / 32, B, 0, stream>>>(a1, W2, h2, NN);
    {
        int total = NN * (DO / 4);
        k_agg_csr<DO, false><<<(total + B - 1) / B, B, 0, stream>>>(
            h2, dinv, row_ptr, cnt, src_sorted, b2, out, NN);
    }
}

// Round 3
// 242.095 us; speedup vs baseline: 6.6230x; 1.5163x over previous
//
#include <hip/hip_runtime.h>

// GCN: out = GCNConv2( relu( GCNConv1(x) ) )
// CSR aggregation (no float atomics). Round 2->3: replaced the single-block
// 134us scan (0.14% occupancy) with a 3-phase parallel scan.

constexpr int NN = 50000;
constexpr int NE = 800000;
constexpr int DI = 96;
constexpr int DH = 96;
constexpr int DO = 48;

constexpr int SCAN_B  = 256;
constexpr int SCAN_NB = (NN + SCAN_B - 1) / SCAN_B;   // 196 (fits one 256-thread scan block)

// ---------------- CSR build ----------------

__global__ void k_zero_int(int* __restrict__ p, int n) {
    int i = blockIdx.x * blockDim.x + threadIdx.x;
    if (i < n) p[i] = 0;
}

__global__ void k_count(const int* __restrict__ dst, int* __restrict__ cnt, int e) {
    int i = blockIdx.x * blockDim.x + threadIdx.x;
    if (i < e) atomicAdd(&cnt[dst[i]], 1);
}

// phase 1: per-block sum of cnt
__global__ __launch_bounds__(SCAN_B) void k_blocksum(const int* __restrict__ cnt,
                                                     int* __restrict__ bsum, int n) {
    __shared__ int sh[SCAN_B];
    const int t = threadIdx.x;
    const int i = blockIdx.x * SCAN_B + t;
    sh[t] = (i < n) ? cnt[i] : 0;
    __syncthreads();
#pragma unroll
    for (int off = SCAN_B / 2; off > 0; off >>= 1) {
        if (t < off) sh[t] += sh[t + off];
        __syncthreads();
    }
    if (t == 0) bsum[blockIdx.x] = sh[0];
}

// phase 2: single block, exclusive scan of block sums in place (nb <= 256)
__global__ __launch_bounds__(SCAN_B) void k_scan_bsum(int* __restrict__ bsum, int nb) {
    __shared__ int sh[SCAN_B];
    const int t = threadIdx.x;
    const int v = (t < nb) ? bsum[t] : 0;
    sh[t] = v;
    __syncthreads();
#pragma unroll
    for (int off = 1; off < SCAN_B; off <<= 1) {
        int x = sh[t];
        int a = (t >= off) ? sh[t - off] : 0;
        __syncthreads();
        sh[t] = x + a;
        __syncthreads();
    }
    if (t < nb) bsum[t] = sh[t] - v;  // exclusive
}

// phase 3: block-local exclusive scan + block offset -> row_ptr/cursor, dinv
__global__ __launch_bounds__(SCAN_B) void k_write_csr(const int* __restrict__ cnt,
                                                      const int* __restrict__ bsum,
                                                      int* __restrict__ row_ptr,
                                                      int* __restrict__ cursor,
                                                      float* __restrict__ dinv, int n) {
    __shared__ int sh[SCAN_B];
    const int t = threadIdx.x;
    const int i = blockIdx.x * SCAN_B + t;
    const int v = (i < n) ? cnt[i] : 0;
    sh[t] = v;
    __syncthreads();
#pragma unroll
    for (int off = 1; off < SCAN_B; off <<= 1) {
        int x = sh[t];
        int a = (t >= off) ? sh[t - off] : 0;
        __syncthreads();
        sh[t] = x + a;
        __syncthreads();
    }
    if (i < n) {
        int excl = sh[t] - v + bsum[blockIdx.x];
        row_ptr[i] = excl;
        cursor[i]  = excl;
        dinv[i]    = rsqrtf((float)(v + 1));  // +1 self-loop
    }
}

__global__ void k_fill(const int* __restrict__ src, const int* __restrict__ dst,
                       int* __restrict__ cursor, int* __restrict__ src_sorted, int e) {
    int i = blockIdx.x * blockDim.x + threadIdx.x;
    if (i < e) {
        int pos = atomicAdd(&cursor[dst[i]], 1);
        src_sorted[pos] = src[i];
    }
}

// ---------------- dense GEMM: H[n][DOUT] = X[n][DI] @ W[DI][DOUT] ----------------

template<int DOUT>
__global__ __launch_bounds__(256) void k_gemm(const float* __restrict__ X,
                                              const float* __restrict__ W,
                                              float* __restrict__ H, int n) {
    constexpr int ROWS = 32;
    constexpr int CPT  = DOUT / 16;
    constexpr int RPT  = 2;

    __shared__ float ws[DI * DOUT];
    __shared__ float xs[ROWS][DI];

    const int tid  = threadIdx.x;
    const int row0 = blockIdx.x * ROWS;

    for (int i = tid; i < DI * DOUT; i += 256) ws[i] = W[i];

    {
        const float4* Xv  = reinterpret_cast<const float4*>(X + (size_t)row0 * DI);
        float4*       xsv = reinterpret_cast<float4*>(&xs[0][0]);
        const int nv   = ROWS * DI / 4;
        const int maxv = ((n - row0) * DI) / 4;
        for (int i = tid; i < nv; i += 256) {
            float4 v = (i < maxv) ? Xv[i] : float4{0.f, 0.f, 0.f, 0.f};
            xsv[i] = v;
        }
    }
    __syncthreads();

    const int cg = tid & 15;
    const int rg = tid >> 4;

    float acc[RPT][CPT];
#pragma unroll
    for (int i = 0; i < RPT; ++i)
#pragma unroll
        for (int j = 0; j < CPT; ++j) acc[i][j] = 0.f;

    for (int k = 0; k < DI; ++k) {
        float xv[RPT];
#pragma unroll
        for (int i = 0; i < RPT; ++i) xv[i] = xs[rg * RPT + i][k];
#pragma unroll
        for (int j = 0; j < CPT; ++j) {
            float wv = ws[k * DOUT + cg * CPT + j];
#pragma unroll
            for (int i = 0; i < RPT; ++i) acc[i][j] += xv[i] * wv;
        }
    }

#pragma unroll
    for (int i = 0; i < RPT; ++i) {
        int row = row0 + rg * RPT + i;
        if (row < n) {
#pragma unroll
            for (int j = 0; j < CPT; ++j)
                H[(size_t)row * DOUT + cg * CPT + j] = acc[i][j];
        }
    }
}

// ---------------- CSR aggregation (fused self-loop + bias [+ relu]) ----------------

template<int D, bool RELU>
__global__ __launch_bounds__(256) void k_agg_csr(const float* __restrict__ h,
                                                 const float* __restrict__ dinv,
                                                 const int* __restrict__ row_ptr,
                                                 const int* __restrict__ cnt,
                                                 const int* __restrict__ src_sorted,
                                                 const float* __restrict__ bias,
                                                 float* __restrict__ out, int n) {
    constexpr int G = D / 4;
    int t = blockIdx.x * blockDim.x + threadIdx.x;
    if (t >= n * G) return;
    const int node = t / G;
    const int g    = t % G;

    const float4* h4 = reinterpret_cast<const float4*>(h);
    const float di = dinv[node];
    const float s0 = di * di;

    float4 hv = h4[(size_t)node * G + g];
    float ax = s0 * hv.x, ay = s0 * hv.y, az = s0 * hv.z, aw = s0 * hv.w;

    const int beg = row_ptr[node];
    const int end = beg + cnt[node];
    for (int k = beg; k < end; ++k) {
        int s = src_sorted[k];
        float nrm = di * dinv[s];
        float4 v = h4[(size_t)s * G + g];
        ax += nrm * v.x;
        ay += nrm * v.y;
        az += nrm * v.z;
        aw += nrm * v.w;
    }

    float4 bv = reinterpret_cast<const float4*>(bias)[g];
    ax += bv.x; ay += bv.y; az += bv.z; aw += bv.w;
    if (RELU) {
        ax = fmaxf(ax, 0.f); ay = fmaxf(ay, 0.f);
        az = fmaxf(az, 0.f); aw = fmaxf(aw, 0.f);
    }
    reinterpret_cast<float4*>(out)[t] = float4{ax, ay, az, aw};
}

// ---------------- launch ----------------

extern "C" void kernel_launch(void* const* d_in, const int* in_sizes, int n_in,
                              void* d_out, int out_size, void* d_ws, size_t ws_size,
                              hipStream_t stream) {
    const float* x   = (const float*)d_in[0];
    const int*   ei  = (const int*)d_in[1];   // [2][NE] int32
    const float* W1  = (const float*)d_in[2];
    const float* b1  = (const float*)d_in[3];
    const float* W2  = (const float*)d_in[4];
    const float* b2  = (const float*)d_in[5];
    float*       out = (float*)d_out;

    const int* srcv = ei;
    const int* dstv = ei + NE;

    // workspace layout
    char* p = (char*)d_ws;
    float* dinv       = (float*)p;            p += (size_t)NN * 4;
    float* h1         = (float*)p;            p += (size_t)NN * DH * 4;   // reused as h2
    float* a1         = (float*)p;            p += (size_t)NN * DH * 4;
    int*   cnt        = (int*)p;              p += (size_t)NN * 4;
    int*   row_ptr    = (int*)p;              p += (size_t)NN * 4;
    int*   cursor     = (int*)p;              p += (size_t)NN * 4;
    int*   src_sorted = (int*)p;              p += (size_t)NE * 4;
    int*   bsum       = (int*)p;              p += (size_t)SCAN_NB * 4;

    const int B = 256;

    // CSR build + dinv
    k_zero_int<<<(NN + B - 1) / B, B, 0, stream>>>(cnt, NN);
    k_count<<<(NE + B - 1) / B, B, 0, stream>>>(dstv, cnt, NE);
    k_blocksum<<<SCAN_NB, SCAN_B, 0, stream>>>(cnt, bsum, NN);
    k_scan_bsum<<<1, SCAN_B, 0, stream>>>(bsum, SCAN_NB);
    k_write_csr<<<SCAN_NB, SCAN_B, 0, stream>>>(cnt, bsum, row_ptr, cursor, dinv, NN);
    k_fill<<<(NE + B - 1) / B, B, 0, stream>>>(srcv, dstv, cursor, src_sorted, NE);

    // layer 1: h1 = x@W1 ; a1 = relu(agg(h1) + b1)
    k_gemm<DH><<<(NN + 31) / 32, B, 0, stream>>>(x, W1, h1, NN);
    {
        int total = NN * (DH / 4);
        k_agg_csr<DH, true><<<(total + B - 1) / B, B, 0, stream>>>(
            h1, dinv, row_ptr, cnt, src_sorted, b1, a1, NN);
    }

    // layer 2: h2 = a1@W2 ; out = agg(h2) + b2
    float* h2 = h1;
    k_gemm<DO><<<(NN + 31) / 32, B, 0, stream>>>(a1, W2, h2, NN);
    {
        int total = NN * (DO / 4);
        k_agg_csr<DO, false><<<(total + B - 1) / B, B, 0, stream>>>(
            h2, dinv, row_ptr, cnt, src_sorted, b2, out, NN);
    }
}

// Round 4
// 217.468 us; speedup vs baseline: 7.3731x; 1.1132x over previous
//
#include <hip/hip_runtime.h>
#include <hip/hip_bf16.h>

// GCN: out = GCNConv2( relu( GCNConv1(x) ) )
// CSR aggregation, h stored as bf16 to halve the gather traffic
// (round 3 showed FETCH = 8 XCDs x full h: traffic ∝ sizeof(h)).

constexpr int NN = 50000;
constexpr int NE = 800000;
constexpr int DI = 96;
constexpr int DH = 96;
constexpr int DO = 48;

constexpr int SCAN_B  = 256;
constexpr int SCAN_NB = (NN + SCAN_B - 1) / SCAN_B;   // 196

typedef unsigned short ushort8 __attribute__((ext_vector_type(8)));

__device__ __forceinline__ float bf2f(unsigned short u) {
    return __uint_as_float(((unsigned int)u) << 16);
}

// ---------------- CSR build ----------------

__global__ void k_zero_int(int* __restrict__ p, int n) {
    int i = blockIdx.x * blockDim.x + threadIdx.x;
    if (i < n) p[i] = 0;
}

__global__ void k_count(const int* __restrict__ dst, int* __restrict__ cnt, int e) {
    int i = blockIdx.x * blockDim.x + threadIdx.x;
    if (i < e) atomicAdd(&cnt[dst[i]], 1);
}

__global__ __launch_bounds__(SCAN_B) void k_blocksum(const int* __restrict__ cnt,
                                                     int* __restrict__ bsum, int n) {
    __shared__ int sh[SCAN_B];
    const int t = threadIdx.x;
    const int i = blockIdx.x * SCAN_B + t;
    sh[t] = (i < n) ? cnt[i] : 0;
    __syncthreads();
#pragma unroll
    for (int off = SCAN_B / 2; off > 0; off >>= 1) {
        if (t < off) sh[t] += sh[t + off];
        __syncthreads();
    }
    if (t == 0) bsum[blockIdx.x] = sh[0];
}

__global__ __launch_bounds__(SCAN_B) void k_scan_bsum(int* __restrict__ bsum, int nb) {
    __shared__ int sh[SCAN_B];
    const int t = threadIdx.x;
    const int v = (t < nb) ? bsum[t] : 0;
    sh[t] = v;
    __syncthreads();
#pragma unroll
    for (int off = 1; off < SCAN_B; off <<= 1) {
        int x = sh[t];
        int a = (t >= off) ? sh[t - off] : 0;
        __syncthreads();
        sh[t] = x + a;
        __syncthreads();
    }
    if (t < nb) bsum[t] = sh[t] - v;  // exclusive
}

__global__ __launch_bounds__(SCAN_B) void k_write_csr(const int* __restrict__ cnt,
                                                      const int* __restrict__ bsum,
                                                      int* __restrict__ row_ptr,
                                                      int* __restrict__ cursor,
                                                      float* __restrict__ dinv, int n) {
    __shared__ int sh[SCAN_B];
    const int t = threadIdx.x;
    const int i = blockIdx.x * SCAN_B + t;
    const int v = (i < n) ? cnt[i] : 0;
    sh[t] = v;
    __syncthreads();
#pragma unroll
    for (int off = 1; off < SCAN_B; off <<= 1) {
        int x = sh[t];
        int a = (t >= off) ? sh[t - off] : 0;
        __syncthreads();
        sh[t] = x + a;
        __syncthreads();
    }
    if (i < n) {
        int excl = sh[t] - v + bsum[blockIdx.x];
        row_ptr[i] = excl;
        cursor[i]  = excl;
        dinv[i]    = rsqrtf((float)(v + 1));  // +1 self-loop
    }
}

__global__ void k_fill(const int* __restrict__ src, const int* __restrict__ dst,
                       int* __restrict__ cursor, int* __restrict__ src_sorted, int e) {
    int i = blockIdx.x * blockDim.x + threadIdx.x;
    if (i < e) {
        int pos = atomicAdd(&cursor[dst[i]], 1);
        src_sorted[pos] = src[i];
    }
}

// ---------------- dense GEMM: H[n][DOUT] = X[n][DI] @ W[DI][DOUT], H in bf16 ----------------

template<int DOUT>
__global__ __launch_bounds__(256) void k_gemm(const float* __restrict__ X,
                                              const float* __restrict__ W,
                                              __hip_bfloat16* __restrict__ H, int n) {
    constexpr int ROWS = 32;
    constexpr int CPT  = DOUT / 16;
    constexpr int RPT  = 2;

    __shared__ float ws[DI * DOUT];
    __shared__ float xs[ROWS][DI];

    const int tid  = threadIdx.x;
    const int row0 = blockIdx.x * ROWS;

    for (int i = tid; i < DI * DOUT; i += 256) ws[i] = W[i];

    {
        const float4* Xv  = reinterpret_cast<const float4*>(X + (size_t)row0 * DI);
        float4*       xsv = reinterpret_cast<float4*>(&xs[0][0]);
        const int nv   = ROWS * DI / 4;
        const int maxv = ((n - row0) * DI) / 4;
        for (int i = tid; i < nv; i += 256) {
            float4 v = (i < maxv) ? Xv[i] : float4{0.f, 0.f, 0.f, 0.f};
            xsv[i] = v;
        }
    }
    __syncthreads();

    const int cg = tid & 15;
    const int rg = tid >> 4;

    float acc[RPT][CPT];
#pragma unroll
    for (int i = 0; i < RPT; ++i)
#pragma unroll
        for (int j = 0; j < CPT; ++j) acc[i][j] = 0.f;

    for (int k = 0; k < DI; ++k) {
        float xv[RPT];
#pragma unroll
        for (int i = 0; i < RPT; ++i) xv[i] = xs[rg * RPT + i][k];
#pragma unroll
        for (int j = 0; j < CPT; ++j) {
            float wv = ws[k * DOUT + cg * CPT + j];
#pragma unroll
            for (int i = 0; i < RPT; ++i) acc[i][j] += xv[i] * wv;
        }
    }

#pragma unroll
    for (int i = 0; i < RPT; ++i) {
        int row = row0 + rg * RPT + i;
        if (row < n) {
#pragma unroll
            for (int j = 0; j < CPT; ++j)
                H[(size_t)row * DOUT + cg * CPT + j] = __float2bfloat16(acc[i][j]);
        }
    }
}

// ---------------- CSR aggregation over bf16 h (fused self-loop + bias [+ relu]) ----------------
// thread = (node, 8-dim group); 16B gathers; f32 accumulate; single f32 write.

template<int D, bool RELU>
__global__ __launch_bounds__(256) void k_agg_csr(const unsigned short* __restrict__ h,
                                                 const float* __restrict__ dinv,
                                                 const int* __restrict__ row_ptr,
                                                 const int* __restrict__ cnt,
                                                 const int* __restrict__ src_sorted,
                                                 const float* __restrict__ bias,
                                                 float* __restrict__ out, int n) {
    constexpr int G = D / 8;
    int t = blockIdx.x * blockDim.x + threadIdx.x;
    if (t >= n * G) return;
    const int node = t / G;
    const int g    = t % G;

    const ushort8* h8 = reinterpret_cast<const ushort8*>(h);
    const float di = dinv[node];
    const float s0 = di * di;

    float acc[8];
    {
        ushort8 hv = h8[(size_t)node * G + g];
#pragma unroll
        for (int j = 0; j < 8; ++j) acc[j] = s0 * bf2f(hv[j]);
    }

    const int beg = row_ptr[node];
    const int end = beg + cnt[node];
    for (int k = beg; k < end; ++k) {
        int s = src_sorted[k];             // broadcast across the node's G threads
        float nrm = di * dinv[s];
        ushort8 v = h8[(size_t)s * G + g]; // 16B/lane coalesced row gather
#pragma unroll
        for (int j = 0; j < 8; ++j) acc[j] += nrm * bf2f(v[j]);
    }

    const float4* b4 = reinterpret_cast<const float4*>(bias);
    float4 b0 = b4[g * 2], b1 = b4[g * 2 + 1];
    acc[0] += b0.x; acc[1] += b0.y; acc[2] += b0.z; acc[3] += b0.w;
    acc[4] += b1.x; acc[5] += b1.y; acc[6] += b1.z; acc[7] += b1.w;
    if (RELU) {
#pragma unroll
        for (int j = 0; j < 8; ++j) acc[j] = fmaxf(acc[j], 0.f);
    }
    float4* o4 = reinterpret_cast<float4*>(out + (size_t)node * D + g * 8);
    o4[0] = float4{acc[0], acc[1], acc[2], acc[3]};
    o4[1] = float4{acc[4], acc[5], acc[6], acc[7]};
}

// ---------------- launch ----------------

extern "C" void kernel_launch(void* const* d_in, const int* in_sizes, int n_in,
                              void* d_out, int out_size, void* d_ws, size_t ws_size,
                              hipStream_t stream) {
    const float* x   = (const float*)d_in[0];
    const int*   ei  = (const int*)d_in[1];   // [2][NE] int32
    const float* W1  = (const float*)d_in[2];
    const float* b1  = (const float*)d_in[3];
    const float* W2  = (const float*)d_in[4];
    const float* b2  = (const float*)d_in[5];
    float*       out = (float*)d_out;

    const int* srcv = ei;
    const int* dstv = ei + NE;

    // workspace layout (16B-aligned blocks)
    char* p = (char*)d_ws;
    float* dinv       = (float*)p;            p += (size_t)NN * 4;
    float* a1         = (float*)p;            p += (size_t)NN * DH * 4;
    __hip_bfloat16* h1 = (__hip_bfloat16*)p;  p += (size_t)NN * DH * 2;   // reused as h2
    int*   cnt        = (int*)p;              p += (size_t)NN * 4;
    int*   row_ptr    = (int*)p;              p += (size_t)NN * 4;
    int*   cursor     = (int*)p;              p += (size_t)NN * 4;
    int*   src_sorted = (int*)p;              p += (size_t)NE * 4;
    int*   bsum       = (int*)p;              p += (size_t)SCAN_NB * 4;

    const int B = 256;

    // CSR build + dinv
    k_zero_int<<<(NN + B - 1) / B, B, 0, stream>>>(cnt, NN);
    k_count<<<(NE + B - 1) / B, B, 0, stream>>>(dstv, cnt, NE);
    k_blocksum<<<SCAN_NB, SCAN_B, 0, stream>>>(cnt, bsum, NN);
    k_scan_bsum<<<1, SCAN_B, 0, stream>>>(bsum, SCAN_NB);
    k_write_csr<<<SCAN_NB, SCAN_B, 0, stream>>>(cnt, bsum, row_ptr, cursor, dinv, NN);
    k_fill<<<(NE + B - 1) / B, B, 0, stream>>>(srcv, dstv, cursor, src_sorted, NE);

    // layer 1: h1 = bf16(x@W1) ; a1 = relu(agg(h1) + b1)
    k_gemm<DH><<<(NN + 31) / 32, B, 0, stream>>>(x, W1, h1, NN);
    {
        int total = NN * (DH / 8);
        k_agg_csr<DH, true><<<(total + B - 1) / B, B, 0, stream>>>(
            (const unsigned short*)h1, dinv, row_ptr, cnt, src_sorted, b1, a1, NN);
    }

    // layer 2: h2 = bf16(a1@W2) ; out = agg(h2) + b2
    __hip_bfloat16* h2 = h1;
    k_gemm<DO><<<(NN + 31) / 32, B, 0, stream>>>(a1, W2, h2, NN);
    {
        int total = NN * (DO / 8);
        k_agg_csr<DO, false><<<(total + B - 1) / B, B, 0, stream>>>(
            (const unsigned short*)h2, dinv, row_ptr, cnt, src_sorted, b2, out, NN);
    }
}